// Round 16
// baseline (89.308 us; speedup 1.0000x reference)
//
#include <hip/hip_runtime.h>

#define BATCH 8
#define NBOX 4096
#define NCLS 80
#define THRESH 0.8f
#define EPSV 1e-9f
#define LCAP 512   // LDS segment capacity; actual class sizes ~51 +/- 7

// One single-wave block per (batch, class): compact class members into LDS
// (stable, ascending original index), all-pairs containment sums with exact
// j != i test, then write final masked boxes + keep flags directly.
__global__ __launch_bounds__(64) void class_filter_kernel(
    const float* __restrict__ boxes,   // [B,N,4]
    const int* __restrict__ cls,       // [B,N]
    float* __restrict__ out)           // [B*N*4] masked boxes, then [B*N] keep
{
    __shared__ float4 lbox[LCAP];
    __shared__ float  larea[LCAP];
    __shared__ int    lidx[LCAP];

    const int b = blockIdx.x / NCLS;
    const int c = blockIdx.x % NCLS;
    const int lane = threadIdx.x;

    const float4* bx = reinterpret_cast<const float4*>(boxes) + (size_t)b * NBOX;
    const int* cl = cls + (size_t)b * NBOX;

    // wave-synchronous stable compaction (no __syncthreads needed inside:
    // no lane reads another lane's LDS write until after the barrier below)
    int len = 0;
    for (int base = 0; base < NBOX; base += 64) {
        const int idx = base + lane;
        const bool m = (cl[idx] == c);
        const unsigned long long mask = __ballot(m);
        const int pos = len + __popcll(mask & ((1ull << lane) - 1ull));
        if (m && pos < LCAP) {
            float4 bb = bx[idx];
            lbox[pos]  = bb;
            larea[pos] = (bb.z - bb.x) * (bb.w - bb.y);
            lidx[pos]  = idx;
        }
        len += (int)__popcll(mask);
    }
    __syncthreads();

    float*  keepOut = out + (size_t)BATCH * NBOX * 4;
    float4* boxOut  = reinterpret_cast<float4*>(out);

    if (len <= LCAP) {
        // fast path: all-pairs within the LDS segment (ascending index order)
        for (int ib = 0; ib < len; ib += 64) {
            const int ir = ib + lane;
            const bool act = ir < len;
            float4 bi = act ? lbox[ir] : make_float4(2.f, 2.f, -1.f, -1.f);
            const int mi = act ? lidx[ir] : -1;
            float sum = 0.f;
            for (int k = 0; k < len; ++k) {          // broadcast LDS reads
                float4 bj = lbox[k];
                float m = fmaxf(fmaxf(bi.x - bj.x, bi.y - bj.y),
                                fmaxf(bj.z - bi.z, bj.w - bi.w));
                bool cont = (m <= 0.f) && (lidx[k] != mi);  // exact self-exclusion
                sum += cont ? larea[k] : 0.f;
            }
            if (act) {
                float area = larea[ir];
                float kf = (sum <= THRESH * (area + EPSV)) ? 1.f : 0.f;
                const int g = b * NBOX + mi;
                boxOut[g] = make_float4(bi.x * kf, bi.y * kf, bi.z * kf, bi.w * kf);
                keepOut[g] = kf;
            }
        }
    } else {
        // general fallback (not expected with this input): direct global scan
        for (int ibase = 0; ibase < NBOX; ibase += 64) {
            const int i = ibase + lane;
            if (cl[i] != c) continue;
            float4 bi = bx[i];
            float area = (bi.z - bi.x) * (bi.w - bi.y);
            float sum = 0.f;
            for (int j = 0; j < NBOX; ++j) {
                if (cl[j] != c || j == i) continue;
                float4 bj = bx[j];
                float m = fmaxf(fmaxf(bi.x - bj.x, bi.y - bj.y),
                                fmaxf(bj.z - bi.z, bj.w - bi.w));
                sum += (m <= 0.f) ? (bj.z - bj.x) * (bj.w - bj.y) : 0.f;
            }
            float kf = (sum <= THRESH * (area + EPSV)) ? 1.f : 0.f;
            const int g = b * NBOX + i;
            boxOut[g] = make_float4(bi.x * kf, bi.y * kf, bi.z * kf, bi.w * kf);
            keepOut[g] = kf;
        }
    }
}

extern "C" void kernel_launch(void* const* d_in, const int* in_sizes, int n_in,
                              void* d_out, int out_size, void* d_ws, size_t ws_size,
                              hipStream_t stream) {
    const float* boxes = (const float*)d_in[0];
    const int*   cls   = (const int*)d_in[1];
    float* out = (float*)d_out;

    class_filter_kernel<<<BATCH * NCLS, 64, 0, stream>>>(boxes, cls, out);
}

// Round 17
// 67.281 us; speedup vs baseline: 1.3274x; 1.3274x over previous
//
#include <hip/hip_runtime.h>

#define BATCH 8
#define NBOX 4096
#define NCLS 80
#define THRESH 0.8f
#define EPSV 1e-9f
#define LCAP 512            // LDS segment capacity; class sizes ~51 +/- 7
#define WAVES 4
#define TPB (WAVES * 64)    // 256 threads
#define PERW (NBOX / WAVES) // 1024 indices per wave
#define WITER (PERW / 64)   // 16 ballot iterations per wave

// One 4-wave block per (batch, class): two-pass stable compaction into LDS
// (wave ranges are index-ordered, so segment order = ascending original index),
// all-pairs containment with exact j != i test, direct final write.
__global__ __launch_bounds__(TPB) void class_filter_kernel(
    const float* __restrict__ boxes,   // [B,N,4]
    const int* __restrict__ cls,       // [B,N]
    float* __restrict__ out)           // [B*N*4] masked boxes, then [B*N] keep
{
    __shared__ float4 lbox[LCAP];
    __shared__ float  larea[LCAP];
    __shared__ int    lidx[LCAP];
    __shared__ int    wcnt[WAVES];

    const int b = blockIdx.x / NCLS;
    const int c = blockIdx.x % NCLS;
    const int tid  = threadIdx.x;
    const int w    = tid >> 6;
    const int lane = tid & 63;
    const int w0   = w * PERW;

    const float4* bx = reinterpret_cast<const float4*>(boxes) + (size_t)b * NBOX;
    const int* cl = cls + (size_t)b * NBOX;

    // pass 1: per-wave member count (independent loads -> pipelined)
    int cnt = 0;
#pragma unroll
    for (int it = 0; it < WITER; ++it) {
        const int idx = w0 + it * 64 + lane;
        cnt += (int)__popcll(__ballot(cl[idx] == c));
    }
    if (lane == 0) wcnt[w] = cnt;
    __syncthreads();

    int base = 0, len = 0;
#pragma unroll
    for (int ww = 0; ww < WAVES; ++ww) {
        int v = wcnt[ww];
        if (ww < w) base += v;
        len += v;
    }

    // pass 2: stable scatter into LDS (loads now L1-hot)
    if (len <= LCAP) {
        int run = base;
        for (int it = 0; it < WITER; ++it) {
            const int idx = w0 + it * 64 + lane;
            const bool m = (cl[idx] == c);
            const unsigned long long mask = __ballot(m);
            const int pos = run + (int)__popcll(mask & ((1ull << lane) - 1ull));
            if (m) {
                float4 bb = bx[idx];
                lbox[pos]  = bb;
                larea[pos] = (bb.z - bb.x) * (bb.w - bb.y);
                lidx[pos]  = idx;
            }
            run += (int)__popcll(mask);
        }
    }
    __syncthreads();

    float*  keepOut = out + (size_t)BATCH * NBOX * 4;
    float4* boxOut  = reinterpret_cast<float4*>(out);

    if (len <= LCAP) {
        // all-pairs: i strided across all 256 threads; k ascending (ref FP order)
        for (int ib = 0; ib < len; ib += TPB) {
            const int ir = ib + tid;
            const bool act = ir < len;
            float4 bi = act ? lbox[ir] : make_float4(2.f, 2.f, -1.f, -1.f);
            const int mi = act ? lidx[ir] : -1;
            float sum = 0.f;
            for (int k = 0; k < len; ++k) {          // broadcast LDS reads
                float4 bj = lbox[k];
                float m = fmaxf(fmaxf(bi.x - bj.x, bi.y - bj.y),
                                fmaxf(bj.z - bi.z, bj.w - bi.w));
                bool cont = (m <= 0.f) && (lidx[k] != mi);  // exact self-exclusion
                sum += cont ? larea[k] : 0.f;
            }
            if (act) {
                float area = larea[ir];
                float kf = (sum <= THRESH * (area + EPSV)) ? 1.f : 0.f;
                const int g = b * NBOX + mi;
                boxOut[g] = make_float4(bi.x * kf, bi.y * kf, bi.z * kf, bi.w * kf);
                keepOut[g] = kf;
            }
        }
    } else {
        // general fallback (not expected with this input): direct global scan
        for (int i0 = 0; i0 < NBOX; i0 += TPB) {
            const int i = i0 + tid;
            if (cl[i] != c) continue;
            float4 bi = bx[i];
            float area = (bi.z - bi.x) * (bi.w - bi.y);
            float sum = 0.f;
            for (int j = 0; j < NBOX; ++j) {
                if (cl[j] != c || j == i) continue;
                float4 bj = bx[j];
                float m = fmaxf(fmaxf(bi.x - bj.x, bi.y - bj.y),
                                fmaxf(bj.z - bi.z, bj.w - bi.w));
                sum += (m <= 0.f) ? (bj.z - bj.x) * (bj.w - bj.y) : 0.f;
            }
            float kf = (sum <= THRESH * (area + EPSV)) ? 1.f : 0.f;
            const int g = b * NBOX + i;
            boxOut[g] = make_float4(bi.x * kf, bi.y * kf, bi.z * kf, bi.w * kf);
            keepOut[g] = kf;
        }
    }
}

extern "C" void kernel_launch(void* const* d_in, const int* in_sizes, int n_in,
                              void* d_out, int out_size, void* d_ws, size_t ws_size,
                              hipStream_t stream) {
    const float* boxes = (const float*)d_in[0];
    const int*   cls   = (const int*)d_in[1];
    float* out = (float*)d_out;

    class_filter_kernel<<<BATCH * NCLS, TPB, 0, stream>>>(boxes, cls, out);
}